// Round 1
// 479.466 us; speedup vs baseline: 1.0943x; 1.0943x over previous
//
#include <hip/hip_runtime.h>
#include <stdint.h>

// ---------------------------------------------------------------------------
// QuantizedLinear: out[M,N] = x[M,K] @ dequant(Wpacked)[N,K]^T
//   M = 8192, K = 4096, N = 4096
// R6: prepass unchanged. GEMM ported to the 256x256 8-phase template
// (learn_hip m194-m201): BK=64, 8 waves (2Mx4N), 128 KiB double-buffered LDS,
// 16x16x32 bf16 MFMA, counted vmcnt(6) (never 0 in steady state), XOR-8
// 16B-block LDS swizzle via pre-swizzled global source, s_setprio around
// MFMA clusters, bijective XCD blockIdx swizzle.
//
// Schedule per K-tile T (buffer b = T&1), 4 phases = 4 C-quadrants:
//   ph1 (qm0,qn0): ds_read A-qm0 (8xb128) + B-qn0 (4xb128); stage A-qm1(T+1)
//   ph2 (qm0,qn1): ds_read B-qn1 (4);                       stage A-qm0(T+2)
//   ph3 (qm1,qn0): ds_read A-qm1 (8);                       stage B-qn0(T+2)
//   ph4 (qm1,qn1): (regs cached);     stage B-qn1(T+2); vmcnt(6); barrier
// Each phase: [ds_reads | stage issue] barrier; lgkmcnt(0); setprio(1);
// 16 MFMA; setprio(0); barrier.
// Race safety: a staged half overwrites an LDS region whose LAST ds_read was
// in a strictly earlier phase; the end-of-phase barrier orders those reads
// (drained by each wave's own lgkmcnt(0) pre-MFMA) before the stage issue.
// vmcnt(6) at ph4 = 3 half-tiles (6 loads) in flight; drains tile T+1 fully.
// ---------------------------------------------------------------------------

typedef short short8  __attribute__((ext_vector_type(8)));    // 8 bf16 = 4 VGPR
typedef float floatx4 __attribute__((ext_vector_type(4)));    // 16x16 MFMA acc

#define BK 64

// round-to-nearest-even fp32 -> bf16 (returned in low 16 bits)
__device__ __forceinline__ uint32_t f2bf(float f) {
  union { float f; uint32_t u; } v; v.f = f;
  return (v.u + 0x7FFFu + ((v.u >> 16) & 1u)) >> 16;
}

// async global->LDS, 16B per lane; LDS dest is wave-uniform base + lane*16
__device__ __forceinline__ void async_copy16(const void* g, void* l) {
  __builtin_amdgcn_global_load_lds(
      (const __attribute__((address_space(1))) uint32_t*)g,
      (__attribute__((address_space(3))) uint32_t*)l, 16, 0, 0);
}

// ----------------- fused prepass: x -> bf16  and  W -> bf16 ----------------
__global__ void prep_kernel(const float4* __restrict__ x, uint4* __restrict__ xb,
                            int xblocks,
                            const int* __restrict__ wp, const float* __restrict__ cent,
                            const float* __restrict__ scales,
                            unsigned short* __restrict__ wb, int K) {
  if ((int)blockIdx.x < xblocks) {
    int t = blockIdx.x * blockDim.x + threadIdx.x;
    float4 v0 = x[4 * t + 0];
    float4 v1 = x[4 * t + 1];
    float4 v2 = x[4 * t + 2];
    float4 v3 = x[4 * t + 3];
    uint4 o0, o1;
    o0.x = f2bf(v0.x) | (f2bf(v0.y) << 16);
    o0.y = f2bf(v0.z) | (f2bf(v0.w) << 16);
    o0.z = f2bf(v1.x) | (f2bf(v1.y) << 16);
    o0.w = f2bf(v1.z) | (f2bf(v1.w) << 16);
    o1.x = f2bf(v2.x) | (f2bf(v2.y) << 16);
    o1.y = f2bf(v2.z) | (f2bf(v2.w) << 16);
    o1.z = f2bf(v3.x) | (f2bf(v3.y) << 16);
    o1.w = f2bf(v3.z) | (f2bf(v3.w) << 16);
    xb[2 * t]     = o0;
    xb[2 * t + 1] = o1;
  } else {
    __shared__ float lut[16];
    if (threadIdx.x < 16) lut[threadIdx.x] = cent[threadIdx.x];
    __syncthreads();
    int u = (blockIdx.x - xblocks) * blockDim.x + threadIdx.x;
    const int tpr = K >> 4;            // threads per row = 256 (pow2)
    int o = u / tpr;
    int j = u & (tpr - 1);
    const int* base = wp + (size_t)o * (K >> 1) + j * 8;
    const int4 p0 = *(const int4*)(base);
    const int4 p1 = *(const int4*)(base + 4);
    int kbase = j * 16;                // 16 weights, single 64-block
    float s = scales[(size_t)o * (K >> 6) + (kbase >> 6)];
    int pb[8] = {p0.x, p0.y, p0.z, p0.w, p1.x, p1.y, p1.z, p1.w};
    uint32_t w32[8];
#pragma unroll
    for (int i = 0; i < 8; ++i) {
      unsigned b = (unsigned)pb[i] & 0xFFu;
      uint32_t hi = f2bf(lut[b >> 4] * s);   // first element of the byte
      uint32_t lo = f2bf(lut[b & 15] * s);   // second element
      w32[i] = hi | (lo << 16);
    }
    uint4* dst = (uint4*)(wb + (size_t)o * K + kbase);
    dst[0] = make_uint4(w32[0], w32[1], w32[2], w32[3]);
    dst[1] = make_uint4(w32[4], w32[5], w32[6], w32[7]);
  }
}

// ------------------------------ main GEMM ----------------------------------
// A[M,K] bf16, B[N,K] bf16 (B^T layout), C[M,N] fp32.
// LDS layout per buffer (64 KiB): A tile [256 rows][64 bf16] then B tile.
// 16B-slot (row, p) holds global 16B-block p ^ (row&7)  (involution):
//   write side: lane l (srow=l>>3, p=l&7) sources global block (l&7)^srow;
//   read  side: logical block g at row r lives at slot g ^ (r&7).
// Read conflict-freedom: a frag ds_read_b128 has row = base + (lane&15),
// block = (4s + (lane>>4)) ^ (lane&7): every 8 consecutive lanes hit 8
// distinct 16B blocks = all 32 banks.
__global__ __launch_bounds__(512, 2) void gemm_bt8(const unsigned short* __restrict__ A,
                                                   const unsigned short* __restrict__ B,
                                                   float* __restrict__ C,
                                                   int M, int N, int K) {
  __shared__ unsigned short lds[65536];  // 128 KiB: 2 x (A 16K shorts | B 16K shorts)
  const int tid  = threadIdx.x;
  const int lane = tid & 63;
  const int w    = tid >> 6;     // wave 0..7
  const int wm   = w >> 2;       // 2 waves in M
  const int wn   = w & 3;        // 4 waves in N

  // bijective XCD-aware block swizzle (nwg % 8 == 0 here: 512 blocks)
  const int nbx = N >> 8;
  const int nwg = gridDim.x;
  const int wg  = blockIdx.x;
  const int swz = ((nwg & 7) == 0) ? ((wg & 7) * (nwg >> 3) + (wg >> 3)) : wg;
  const int bm  = (swz / nbx) << 8;
  const int bn  = (swz % nbx) << 8;

  // ---- staging: pre-swizzled global source, linear LDS dest --------------
  const int srow = lane >> 3;                 // row within an 8-row chunk
  const int sblk = (lane & 7) ^ srow;         // pre-swizzled global 16B-block
  const size_t goff = (size_t)srow * K + sblk * 8;   // shorts
  const unsigned short* Ag = A + (size_t)bm * K + goff;
  const unsigned short* Bg = B + (size_t)bn * K + goff;

  const int nt = K / BK;

  // A half qm: LDS rows {qm*64+[0,64), 128+qm*64+[0,64)}; 2 issues x 8KiB.
  auto stageA = [&](int buf, int kt, int qm) {
#pragma unroll
    for (int i = 0; i < 2; ++i) {
      const int r0 = i * 128 + qm * 64 + w * 8;          // wave-uniform
      async_copy16(Ag + (size_t)r0 * K + kt,
                   (char*)lds + buf * 65536 + r0 * 128);
    }
  };
  // B half qn: LDS rows {qn*32 + j*64 + [0,32) : j=0..3}; waves 0-3 -> first
  // chunk of the issue, waves 4-7 -> second.
  auto stageB = [&](int buf, int kt, int qn) {
#pragma unroll
    for (int i = 0; i < 2; ++i) {
      const int j  = i * 2 + (w >> 2);
      const int r0 = qn * 32 + j * 64 + (w & 3) * 8;     // wave-uniform
      async_copy16(Bg + (size_t)r0 * K + kt,
                   (char*)lds + buf * 65536 + 32768 + r0 * 128);
    }
  };

  // ---- fragment reads (16x16x32: lane holds row lane&15, k (lane>>4)*8+j) -
  const int lrow  = lane & 15;
  const int g16   = lane >> 4;
  const int e8    = lane & 7;
  const int pblk0 = ((0 + g16) ^ e8) << 3;   // shorts; k-step s=0
  const int pblk1 = ((4 + g16) ^ e8) << 3;   // k-step s=1

  auto ldA = [&](int buf, int qm, int f, int s) -> short8 {
    return *(const short8*)(lds + buf * 32768 +
                            ((wm * 128 + qm * 64 + f * 16 + lrow) << 6) +
                            (s ? pblk1 : pblk0));
  };
  auto ldB = [&](int buf, int qn, int f2, int s) -> short8 {
    return *(const short8*)(lds + buf * 32768 + 16384 +
                            ((wn * 64 + qn * 32 + f2 * 16 + lrow) << 6) +
                            (s ? pblk1 : pblk0));
  };

  floatx4 acc[2][2][4][2] = {};   // [qm][qn][m-frag][n-frag]
  short8 a[4][2];                 // current qm half: [m-frag][k-step]
  short8 b0[2][2], b1[2][2];      // qn halves, cached across qm phases

  // ---- prologue: tile0 (4 halves) + tile1 (3 halves); drain tile0 --------
  stageA(0, 0, 0);
  stageB(0, 0, 0);
  stageB(0, 0, 1);
  stageA(0, 0, 1);
  if (nt > 1) {
    stageA(1, BK, 0);
    stageB(1, BK, 0);
    stageB(1, BK, 1);
    asm volatile("s_waitcnt vmcnt(6)" ::: "memory");
  } else {
    asm volatile("s_waitcnt vmcnt(0)" ::: "memory");
  }
  __builtin_amdgcn_s_barrier();

#pragma unroll 2
  for (int T = 0; T < nt; ++T) {
    const int buf = T & 1;
    const int kt2 = (T + 2) * BK;

    // ---------------- phase 1: (qm0, qn0) ----------------
#pragma unroll
    for (int f = 0; f < 4; ++f) { a[f][0] = ldA(buf, 0, f, 0); a[f][1] = ldA(buf, 0, f, 1); }
#pragma unroll
    for (int f2 = 0; f2 < 2; ++f2) { b0[f2][0] = ldB(buf, 0, f2, 0); b0[f2][1] = ldB(buf, 0, f2, 1); }
    if (T + 1 < nt) stageA(buf ^ 1, (T + 1) * BK, 1);
    __builtin_amdgcn_s_barrier();
    asm volatile("s_waitcnt lgkmcnt(0)" ::: "memory");
    __builtin_amdgcn_s_setprio(1);
#pragma unroll
    for (int f = 0; f < 4; ++f)
#pragma unroll
      for (int f2 = 0; f2 < 2; ++f2) {
        acc[0][0][f][f2] = __builtin_amdgcn_mfma_f32_16x16x32_bf16(a[f][0], b0[f2][0], acc[0][0][f][f2], 0, 0, 0);
        acc[0][0][f][f2] = __builtin_amdgcn_mfma_f32_16x16x32_bf16(a[f][1], b0[f2][1], acc[0][0][f][f2], 0, 0, 0);
      }
    __builtin_amdgcn_s_setprio(0);
    __builtin_amdgcn_s_barrier();

    // ---------------- phase 2: (qm0, qn1) ----------------
#pragma unroll
    for (int f2 = 0; f2 < 2; ++f2) { b1[f2][0] = ldB(buf, 1, f2, 0); b1[f2][1] = ldB(buf, 1, f2, 1); }
    if (T + 2 < nt) stageA(buf, kt2, 0);
    __builtin_amdgcn_s_barrier();
    asm volatile("s_waitcnt lgkmcnt(0)" ::: "memory");
    __builtin_amdgcn_s_setprio(1);
#pragma unroll
    for (int f = 0; f < 4; ++f)
#pragma unroll
      for (int f2 = 0; f2 < 2; ++f2) {
        acc[0][1][f][f2] = __builtin_amdgcn_mfma_f32_16x16x32_bf16(a[f][0], b1[f2][0], acc[0][1][f][f2], 0, 0, 0);
        acc[0][1][f][f2] = __builtin_amdgcn_mfma_f32_16x16x32_bf16(a[f][1], b1[f2][1], acc[0][1][f][f2], 0, 0, 0);
      }
    __builtin_amdgcn_s_setprio(0);
    __builtin_amdgcn_s_barrier();

    // ---------------- phase 3: (qm1, qn0) ----------------
#pragma unroll
    for (int f = 0; f < 4; ++f) { a[f][0] = ldA(buf, 1, f, 0); a[f][1] = ldA(buf, 1, f, 1); }
    if (T + 2 < nt) stageB(buf, kt2, 0);
    __builtin_amdgcn_s_barrier();
    asm volatile("s_waitcnt lgkmcnt(0)" ::: "memory");
    __builtin_amdgcn_s_setprio(1);
#pragma unroll
    for (int f = 0; f < 4; ++f)
#pragma unroll
      for (int f2 = 0; f2 < 2; ++f2) {
        acc[1][0][f][f2] = __builtin_amdgcn_mfma_f32_16x16x32_bf16(a[f][0], b0[f2][0], acc[1][0][f][f2], 0, 0, 0);
        acc[1][0][f][f2] = __builtin_amdgcn_mfma_f32_16x16x32_bf16(a[f][1], b0[f2][1], acc[1][0][f][f2], 0, 0, 0);
      }
    __builtin_amdgcn_s_setprio(0);
    __builtin_amdgcn_s_barrier();

    // ---------------- phase 4: (qm1, qn1) ----------------
    if (T + 2 < nt) stageB(buf, kt2, 1);
    __builtin_amdgcn_s_barrier();
    asm volatile("s_waitcnt lgkmcnt(0)" ::: "memory");
    __builtin_amdgcn_s_setprio(1);
#pragma unroll
    for (int f = 0; f < 4; ++f)
#pragma unroll
      for (int f2 = 0; f2 < 2; ++f2) {
        acc[1][1][f][f2] = __builtin_amdgcn_mfma_f32_16x16x32_bf16(a[f][0], b1[f2][0], acc[1][1][f][f2], 0, 0, 0);
        acc[1][1][f][f2] = __builtin_amdgcn_mfma_f32_16x16x32_bf16(a[f][1], b1[f2][1], acc[1][1][f][f2], 0, 0, 0);
      }
    __builtin_amdgcn_s_setprio(0);
    if (T + 2 < nt) {
      asm volatile("s_waitcnt vmcnt(6)" ::: "memory");   // steady: 3 halves in flight
    } else if (T + 1 < nt) {
      asm volatile("s_waitcnt vmcnt(0)" ::: "memory");   // epilogue drain
    }
    __builtin_amdgcn_s_barrier();
  }

  // ---- C store: 16x16 C/D layout (m89): col = lane&15, row = (lane>>4)*4+reg
#pragma unroll
  for (int qm = 0; qm < 2; ++qm)
#pragma unroll
    for (int qn = 0; qn < 2; ++qn)
#pragma unroll
      for (int f = 0; f < 4; ++f)
#pragma unroll
        for (int f2 = 0; f2 < 2; ++f2) {
          const floatx4 v = acc[qm][qn][f][f2];
          const int row0 = bm + wm * 128 + qm * 64 + f * 16 + g16 * 4;
          const int col  = bn + wn * 64 + qn * 32 + f2 * 16 + lrow;
          float* cp = C + (size_t)row0 * N + col;
#pragma unroll
          for (int r = 0; r < 4; ++r)
            __builtin_nontemporal_store(v[r], cp + (size_t)r * N);
        }
}

// ------------------------- fallback (ws too small) -------------------------
__global__ void naive_kernel(const float* __restrict__ x, const int* __restrict__ wp,
                             const float* __restrict__ cent, const float* __restrict__ scales,
                             float* __restrict__ out, int M, int N, int K) {
  __shared__ float lut[16];
  if (threadIdx.x < 16) lut[threadIdx.x] = cent[threadIdx.x];
  __syncthreads();
  int n = blockIdx.x * blockDim.x + threadIdx.x;
  int m = blockIdx.y;
  if (n >= N || m >= M) return;
  const float* xr = x + (size_t)m * K;
  const int* wr = wp + (size_t)n * (K / 2);
  float acc = 0.f;
  for (int kb = 0; kb < K / 64; ++kb) {
    float s = scales[(size_t)n * (K / 64) + kb];
    float a = 0.f;
    for (int j = 0; j < 32; ++j) {
      unsigned b = (unsigned)wr[kb * 32 + j] & 0xFFu;
      a += xr[kb * 64 + 2 * j] * lut[b >> 4] + xr[kb * 64 + 2 * j + 1] * lut[b & 15];
    }
    acc += a * s;
  }
  out[(size_t)m * N + n] = acc;
}

// ------------------------------- launcher ----------------------------------
extern "C" void kernel_launch(void* const* d_in, const int* in_sizes, int n_in,
                              void* d_out, int out_size, void* d_ws, size_t ws_size,
                              hipStream_t stream) {
  const float* x      = (const float*)d_in[0];
  const int*   wp     = (const int*)d_in[1];
  const float* cent   = (const float*)d_in[2];
  const float* scales = (const float*)d_in[3];
  float*       out    = (float*)d_out;

  const int K = 4096;
  const int M = in_sizes[0] / K;                        // 8192
  const int O = (int)(((size_t)in_sizes[1] * 2) / K);   // 4096

  size_t need = (size_t)M * K * 2 + (size_t)O * K * 2;  // 96 MiB
  const bool shapes_ok = (M % 256 == 0) && (O % 256 == 0) && (K % 64 == 0);
  if (ws_size >= need && shapes_ok) {
    unsigned short* xb = (unsigned short*)d_ws;
    unsigned short* wb = xb + (size_t)M * K;

    int xthreads = M * K / 16;                 // 16 floats per thread
    int xblocks  = xthreads / 256;             // 2048
    int wthreads = O * K / 16;                 // 16 weights per thread
    int wblocks  = wthreads / 256;             // 1024
    prep_kernel<<<xblocks + wblocks, 256, 0, stream>>>(
        (const float4*)x, (uint4*)xb, xblocks, wp, cent, scales, wb, K);

    dim3 grid((M >> 8) * (O >> 8));            // 32 * 16 = 512 blocks
    gemm_bt8<<<grid, 512, 0, stream>>>(xb, wb, out, M, O, K);
  } else {
    dim3 grid((O + 255) / 256, M);
    naive_kernel<<<grid, 256, 0, stream>>>(x, wp, cent, scales, out, M, O, K);
  }
}